// Round 6
// baseline (442.487 us; speedup 1.0000x reference)
//
#include <hip/hip_runtime.h>
#include <hip/hip_bf16.h>

// 3-layer GraphConv (PyG) + softmax, 100k nodes, 1.6M edges, all f32.
// R2: f32 global atomics ~306G/s scattered -> pull-gather wins.
// R3: per-node CSR scatter: 16x write amplification (128us).
// R4: coarse cursors: same-address atomic serialization (376us). Reverted.
// R5: two-phase placement fixed build; NEW top = transform (94us, WRITE 204MB
//     = 8x amp: f-loop stores put 4B into 64 lines per wave-instruction).
// R6: transform rewrite: padded-transposed weights in LDS (float4 broadcast
//     reads), per-f register accumulate, LDS-transpose output staging ->
//     fully-coalesced line-complete flushes. Two passes (t, then acc).

#define RNODES 128
#define NB_MAX 1024
#define CH 8192            // edges per bucketize chunk
#define TB 128             // transform block = nodes per block

// ---------------- transform v2 ---------------------------------------------
// t[n] = act(x[n]) @ Wrel ; acc[n] = act(x[n]) @ Wroot + b
template <int Fin, int Fout, bool RELU>
__global__ void transform2_kernel(const float* __restrict__ x,
                                  const float* __restrict__ Wrel,
                                  const float* __restrict__ Wroot,
                                  const float* __restrict__ bias,
                                  float* __restrict__ t,
                                  float* __restrict__ acc,
                                  int N) {
    constexpr int KP = Fin + 4;          // padded k-stride: 16B-aligned, bank-shifted
    constexpr int OP = Fout + 1;         // odd output pad -> conflict-free writes
    __shared__ float wRelT[Fout * KP];
    __shared__ float wRootT[Fout * KP];
    __shared__ float sB[Fout];
    __shared__ float sOut[TB * OP];

    for (int i = threadIdx.x; i < Fin * Fout; i += TB) {
        int k = i / Fout, f = i - k * Fout;        // global is [k][f], f fast
        wRelT[f * KP + k]  = Wrel[i];
        wRootT[f * KP + k] = Wroot[i];
    }
    if (threadIdx.x < Fout) sB[threadIdx.x] = bias[threadIdx.x];
    __syncthreads();

    const int base = blockIdx.x * TB;
    const int n = base + threadIdx.x;
    const bool valid = (n < N);
    const int lim = min(TB, N - base) * Fout;      // valid flush elements

    float xi[Fin];
    if (valid) {
#pragma unroll
        for (int k = 0; k < Fin; k += 4) {
            float4 v = *(const float4*)(x + (size_t)n * Fin + k);
            if (RELU) {
                v.x = fmaxf(v.x, 0.f); v.y = fmaxf(v.y, 0.f);
                v.z = fmaxf(v.z, 0.f); v.w = fmaxf(v.w, 0.f);
            }
            xi[k] = v.x; xi[k + 1] = v.y; xi[k + 2] = v.z; xi[k + 3] = v.w;
        }
    } else {
#pragma unroll
        for (int k = 0; k < Fin; ++k) xi[k] = 0.f;
    }

    // ---- pass 1: t = xi @ Wrel ----
    for (int f = 0; f < Fout; ++f) {
        float a = 0.f;
#pragma unroll
        for (int k = 0; k < Fin; k += 4) {
            float4 w = *(const float4*)&wRelT[f * KP + k];   // wave-uniform b128
            a = fmaf(xi[k], w.x, fmaf(xi[k + 1], w.y,
                fmaf(xi[k + 2], w.z, fmaf(xi[k + 3], w.w, a))));
        }
        sOut[threadIdx.x * OP + f] = a;
    }
    __syncthreads();
    for (int j = threadIdx.x; j < lim; j += TB)    // coalesced, line-complete
        t[(size_t)base * Fout + j] = sOut[(j / Fout) * OP + (j & (Fout - 1))];
    __syncthreads();

    // ---- pass 2: acc = xi @ Wroot + b ----
    for (int f = 0; f < Fout; ++f) {
        float a = 0.f;
#pragma unroll
        for (int k = 0; k < Fin; k += 4) {
            float4 w = *(const float4*)&wRootT[f * KP + k];
            a = fmaf(xi[k], w.x, fmaf(xi[k + 1], w.y,
                fmaf(xi[k + 2], w.z, fmaf(xi[k + 3], w.w, a))));
        }
        sOut[threadIdx.x * OP + f] = a + sB[f];
    }
    __syncthreads();
    for (int j = threadIdx.x; j < lim; j += TB)
        acc[(size_t)base * Fout + j] = sOut[(j / Fout) * OP + (j & (Fout - 1))];
}

// ---------------- CSR rowptr build (R3-proven) -----------------------------
__global__ void hist_node_kernel(const int* __restrict__ dst, int* __restrict__ counts, int nE) {
    int e = blockIdx.x * blockDim.x + threadIdx.x;
    if (e < nE) atomicAdd(&counts[dst[e]], 1);
}

__global__ void block_sum_kernel(const int* __restrict__ counts, int* __restrict__ partials, int N) {
    __shared__ int s[256];
    int i = blockIdx.x * 256 + threadIdx.x;
    s[threadIdx.x] = (i < N) ? counts[i] : 0;
    __syncthreads();
    for (int off = 128; off > 0; off >>= 1) {
        if (threadIdx.x < off) s[threadIdx.x] += s[threadIdx.x + off];
        __syncthreads();
    }
    if (threadIdx.x == 0) partials[blockIdx.x] = s[0];
}

__global__ void scan_top_kernel(int* __restrict__ partials, int nb) {
    __shared__ int s[512];
    int t = threadIdx.x;
    s[t] = (t < nb) ? partials[t] : 0;
    __syncthreads();
    for (int off = 1; off < 512; off <<= 1) {
        int v = (t >= off) ? s[t - off] : 0;
        __syncthreads();
        s[t] += v;
        __syncthreads();
    }
    if (t < nb) partials[t] = (t == 0) ? 0 : s[t - 1];
}

__global__ void scan_final_kernel(const int* __restrict__ counts,
                                  const int* __restrict__ partials,
                                  int* __restrict__ rowptr, int N, int nE) {
    __shared__ int s[256];
    int t = threadIdx.x;
    int i = blockIdx.x * 256 + t;
    int v = (i < N) ? counts[i] : 0;
    s[t] = v;
    __syncthreads();
    for (int off = 1; off < 256; off <<= 1) {
        int u = (t >= off) ? s[t - off] : 0;
        __syncthreads();
        s[t] += u;
        __syncthreads();
    }
    if (i < N) rowptr[i] = partials[blockIdx.x] + s[t] - v;
    if (i == 0) rowptr[N] = nE;
}

__global__ void init_gcursor_kernel(const int* __restrict__ rowptr,
                                    int* __restrict__ gcursor, int NB) {
    int b = blockIdx.x * blockDim.x + threadIdx.x;
    if (b < NB) gcursor[b] = rowptr[b * RNODES];
}

// ---------------- phase A: chunked coarse bucketize ------------------------
__global__ void bucketize_chunked_kernel(const int* __restrict__ src,
                                         const int* __restrict__ dst,
                                         int* __restrict__ gcursor,
                                         unsigned int* __restrict__ records,
                                         int nE, int NB) {
    __shared__ int chist[NB_MAX];
    __shared__ int sbase[NB_MAX];
    const int e0 = blockIdx.x * CH;
    const int e1 = min(e0 + CH, nE);

    for (int b = threadIdx.x; b < NB; b += blockDim.x) chist[b] = 0;
    __syncthreads();
    for (int e = e0 + threadIdx.x; e < e1; e += blockDim.x)
        atomicAdd(&chist[dst[e] >> 7], 1);
    __syncthreads();
    for (int b = threadIdx.x; b < NB; b += blockDim.x) {
        int c = chist[b];
        sbase[b] = c ? atomicAdd(&gcursor[b], c) : 0;
        chist[b] = 0;   // reuse as local cursor
    }
    __syncthreads();
    for (int e = e0 + threadIdx.x; e < e1; e += blockDim.x) {
        int d = dst[e];
        int b = d >> 7;
        int l = atomicAdd(&chist[b], 1);
        records[sbase[b] + l] = (unsigned int)src[e] | ((unsigned int)(d & 127) << 17);
    }
}

// ---------------- phase B: fine placement via LDS cursors ------------------
__global__ void place_fine_kernel(const unsigned int* __restrict__ records,
                                  const int* __restrict__ rowptr,
                                  int* __restrict__ srcs_sorted, int N) {
    __shared__ int lcur[RNODES];
    const int b    = blockIdx.x;
    const int base = b * RNODES;
    const int nn   = min(RNODES, N - base);
    if (threadIdx.x < nn) lcur[threadIdx.x] = rowptr[base + threadIdx.x];
    __syncthreads();
    const int beg = rowptr[base];
    const int end = rowptr[base + nn];
    for (int i = beg + threadIdx.x; i < end; i += blockDim.x) {
        unsigned int rec = records[i];
        int pos = atomicAdd(&lcur[rec >> 17], 1);
        srcs_sorted[pos] = (int)(rec & 0x1FFFFu);
    }
}

// ---------------- pull aggregation (R3-proven, unroll 8) -------------------
template <int F, int U, bool SOFTMAX>
__global__ void gather_agg_kernel(const float* __restrict__ t,
                                  const int* __restrict__ rowptr,
                                  const int* __restrict__ srcs,
                                  const float* __restrict__ rootacc,
                                  float* __restrict__ out, int N) {
    int tid = blockIdx.x * blockDim.x + threadIdx.x;
    int n = tid / F;
    if (n >= N) return;
    int f = tid & (F - 1);
    const float* tf = t + f;
    int beg = rowptr[n], end = rowptr[n + 1];
    float sum = 0.0f;
    int e = beg;
    for (; e + U <= end; e += U) {
        int s[U];
        float v[U];
#pragma unroll
        for (int u = 0; u < U; ++u) s[u] = srcs[e + u];
#pragma unroll
        for (int u = 0; u < U; ++u) v[u] = tf[(long)s[u] * F];
#pragma unroll
        for (int u = 0; u < U; ++u) sum += v[u];
    }
    for (; e < end; ++e) sum += tf[(long)srcs[e] * F];

    float v = rootacc[(long)n * F + f] + sum;
    if (!SOFTMAX) {
        out[(long)n * F + f] = v;
    } else {
        float o = __shfl_xor(v, 1, 64);
        float m = fmaxf(v, o);
        float ev = __expf(v - m), eo = __expf(o - m);
        out[(long)n * F + f] = ev / (ev + eo);
    }
}

// ---------------- fallback (R2 atomic path) --------------------------------
template <int F>
__global__ void scatter_kernel(const float* __restrict__ t,
                               const int* __restrict__ src,
                               const int* __restrict__ dst,
                               float* __restrict__ acc, int nE) {
    int tid = blockIdx.x * blockDim.x + threadIdx.x;
    int e = tid / F;
    if (e >= nE) return;
    int f = tid & (F - 1);
    atomicAdd(acc + (long)dst[e] * F + f, t[(long)src[e] * F + f]);
}

__global__ void softmax2_kernel(const float* __restrict__ h, float* __restrict__ out, int N) {
    int n = blockIdx.x * blockDim.x + threadIdx.x;
    if (n >= N) return;
    float a = h[2 * n], b = h[2 * n + 1];
    float m = fmaxf(a, b);
    float ea = __expf(a - m), eb = __expf(b - m);
    float inv = 1.0f / (ea + eb);
    out[2 * n] = ea * inv;
    out[2 * n + 1] = eb * inv;
}

extern "C" void kernel_launch(void* const* d_in, const int* in_sizes, int n_in,
                              void* d_out, int out_size, void* d_ws, size_t ws_size,
                              hipStream_t stream) {
    const float* z      = (const float*)d_in[0];
    const int*   ei     = (const int*)d_in[1];
    const float* Wrel1  = (const float*)d_in[2];
    const float* Wroot1 = (const float*)d_in[3];
    const float* b1     = (const float*)d_in[4];
    const float* Wrel2  = (const float*)d_in[5];
    const float* Wroot2 = (const float*)d_in[6];
    const float* b2     = (const float*)d_in[7];
    const float* Wrel3  = (const float*)d_in[8];
    const float* Wroot3 = (const float*)d_in[9];
    const float* b3     = (const float*)d_in[10];

    const int N  = in_sizes[0] / 64;   // 100000
    const int nE = in_sizes[1] / 2;    // 1600000
    const int* src = ei;
    const int* dst = ei + nE;
    const int NB = (N + RNODES - 1) / RNODES;   // 782

    // Float regions (ping-pong, 12.8 MB each):
    //   regionA: [records (build phase)] -> t1[N*32] -> { t2[N*16] | h2[N*16] }
    //   regionB: h1[N*32] -> t3[N*2]
    float* regionA = (float*)d_ws;
    float* regionB = regionA + (size_t)N * 32;
    float* t1 = regionA;
    float* h1 = regionB;
    float* t2 = regionA;
    float* h2 = regionA + (size_t)N * 16;
    float* t3 = regionB;
    float* h3 = regionB + (size_t)N * 2;
    unsigned int* records = (unsigned int*)regionA;   // transient, pre-t1

    // Int region: ncount[N], rowptr[N+1], partials[512], gcursor[NB_MAX], srcs_sorted[nE]
    int* ibase       = (int*)(regionB + (size_t)N * 32);
    int* ncount      = ibase;
    int* rowptr      = ncount + N;
    int* partials    = rowptr + N + 1;
    int* gcursor     = partials + 512;
    int* srcs_sorted = gcursor + NB_MAX;

    size_t needed = (size_t)N * 64 * sizeof(float)
                  + ((size_t)N + (size_t)N + 1 + 512 + NB_MAX + (size_t)nE) * sizeof(int);

    const int B = 256;
    const int nodeBlocksT = (N + TB - 1) / TB;     // transform grid (128/block)
    const int nodeBlocks  = (N + B - 1) / B;
    const int edgeBlocks  = (nE + B - 1) / B;
    const int chunkBlocks = (nE + CH - 1) / CH;
    const bool packOK = (N <= (1 << 17)) && (NB <= NB_MAX) && ((size_t)nE * 4 <= (size_t)N * 32 * 4);

    if (ws_size >= needed && packOK) {
        // ---- build: rowptr ----
        hipMemsetAsync(ncount, 0, (size_t)N * sizeof(int), stream);
        hist_node_kernel<<<edgeBlocks, B, 0, stream>>>(dst, ncount, nE);
        block_sum_kernel<<<nodeBlocks, B, 0, stream>>>(ncount, partials, N);
        scan_top_kernel<<<1, 512, 0, stream>>>(partials, nodeBlocks);
        scan_final_kernel<<<nodeBlocks, B, 0, stream>>>(ncount, partials, rowptr, N, nE);
        // ---- build: two-phase placement ----
        init_gcursor_kernel<<<(NB + B - 1) / B, B, 0, stream>>>(rowptr, gcursor, NB);
        bucketize_chunked_kernel<<<chunkBlocks, B, 0, stream>>>(src, dst, gcursor, records, nE, NB);
        place_fine_kernel<<<NB, B, 0, stream>>>(records, rowptr, srcs_sorted, N);

        // ---- Layer 1: 64 -> 32 ----
        transform2_kernel<64, 32, false><<<nodeBlocksT, TB, 0, stream>>>(z, Wrel1, Wroot1, b1, t1, h1, N);
        gather_agg_kernel<32, 8, false><<<((size_t)N * 32 + B - 1) / B, B, 0, stream>>>(
            t1, rowptr, srcs_sorted, h1, h1, N);

        // ---- Layer 2: 32 -> 16 ----
        transform2_kernel<32, 16, true><<<nodeBlocksT, TB, 0, stream>>>(h1, Wrel2, Wroot2, b2, t2, h2, N);
        gather_agg_kernel<16, 8, false><<<((size_t)N * 16 + B - 1) / B, B, 0, stream>>>(
            t2, rowptr, srcs_sorted, h2, h2, N);

        // ---- Layer 3: 16 -> 2, softmax fused ----
        transform2_kernel<16, 2, true><<<nodeBlocksT, TB, 0, stream>>>(h2, Wrel3, Wroot3, b3, t3, h3, N);
        gather_agg_kernel<2, 4, true><<<((size_t)N * 2 + B - 1) / B, B, 0, stream>>>(
            t3, rowptr, srcs_sorted, h3, (float*)d_out, N);
    } else {
        // ---- fallback: R2 atomic-scatter path ----
        transform2_kernel<64, 32, false><<<nodeBlocksT, TB, 0, stream>>>(z, Wrel1, Wroot1, b1, t1, h1, N);
        scatter_kernel<32><<<((size_t)nE * 32 + B - 1) / B, B, 0, stream>>>(t1, src, dst, h1, nE);
        transform2_kernel<32, 16, true><<<nodeBlocksT, TB, 0, stream>>>(h1, Wrel2, Wroot2, b2, t2, h2, N);
        scatter_kernel<16><<<((size_t)nE * 16 + B - 1) / B, B, 0, stream>>>(t2, src, dst, h2, nE);
        transform2_kernel<16, 2, true><<<nodeBlocksT, TB, 0, stream>>>(h2, Wrel3, Wroot3, b3, t3, h3, N);
        scatter_kernel<2><<<((size_t)nE * 2 + B - 1) / B, B, 0, stream>>>(t3, src, dst, h3, nE);
        softmax2_kernel<<<nodeBlocks, B, 0, stream>>>(h3, (float*)d_out, N);
    }
}

// Round 7
// 338.716 us; speedup vs baseline: 1.3064x; 1.3064x over previous
//
#include <hip/hip_runtime.h>
#include <hip/hip_bf16.h>

// 3-layer GraphConv (PyG) + softmax, 100k nodes, 1.6M edges, all f32.
// R2: f32 global atomics ~306G/s scattered -> pull-gather wins.
// R3: per-node CSR scatter: 16x write amplification (128us).
// R4: coarse cursors: same-address atomic serialization (376us). Reverted.
// R5: two-phase placement fixed build; transform = 94us (store amp 8x).
// R6: LDS-staged transform fixed stores (WRITE 204->46MB) but regressed to
//     133us: ~1024 wave-uniform ds_read_b128/wave + runtime f-loop = LDS-issue
//     + dependency stalls at 6 waves/CU. LDS is the wrong home for weights.
// R7: linear2_kernel: weights read straight from GLOBAL with wave-uniform
//     indices (compiler -> s_load, scalar cache; zero LDS), all Fout accs in
//     registers (16-32 independent FMA chains), rel/root split via gridDim.y
//     (12 waves/CU), contiguous float4 stores (line-complete).

#define RNODES 128
#define NB_MAX 1024
#define CH 8192            // edges per bucketize chunk

// ---------------- linear: out = act(x) @ W (+ bias for root task) ----------
// gridDim.y == 2: y=0 computes t = act(x)@Wrel, y=1 computes acc = act(x)@Wroot + b
template <int Fin, int Fout, bool RELU>
__global__ void linear2_kernel(const float* __restrict__ x,
                               const float* __restrict__ Wrel,
                               const float* __restrict__ Wroot,
                               const float* __restrict__ bias,
                               float* __restrict__ t,
                               float* __restrict__ acc, int N) {
    const bool rootTask = (blockIdx.y != 0);
    const float* __restrict__ W = rootTask ? Wroot : Wrel;
    float* __restrict__ outp    = rootTask ? acc : t;

    int n = blockIdx.x * blockDim.x + threadIdx.x;
    if (n >= N) return;

    float o[Fout];
#pragma unroll
    for (int f = 0; f < Fout; ++f) o[f] = 0.f;

    const float* xr = x + (size_t)n * Fin;
    // k-tiles of 16 keep the unrolled body in I-cache; weight indices stay
    // wave-uniform -> s_load (SMEM path), no LDS, no per-lane VMEM.
    for (int k0 = 0; k0 < Fin; k0 += 16) {
#pragma unroll
        for (int k = 0; k < 16; k += 4) {
            float4 v = *(const float4*)(xr + k0 + k);
            if (RELU) {
                v.x = fmaxf(v.x, 0.f); v.y = fmaxf(v.y, 0.f);
                v.z = fmaxf(v.z, 0.f); v.w = fmaxf(v.w, 0.f);
            }
            const float xv[4] = {v.x, v.y, v.z, v.w};
#pragma unroll
            for (int kk = 0; kk < 4; ++kk) {
                const float* wr = W + (size_t)(k0 + k + kk) * Fout;
#pragma unroll
                for (int f = 0; f < Fout; ++f)
                    o[f] = fmaf(xv[kk], wr[f], o[f]);
            }
        }
    }
    if (rootTask) {
#pragma unroll
        for (int f = 0; f < Fout; ++f) o[f] += bias[f];
    }
    float* op = outp + (size_t)n * Fout;
    if constexpr (Fout >= 4) {
#pragma unroll
        for (int f = 0; f < Fout; f += 4)
            *(float4*)(op + f) = make_float4(o[f], o[f + 1], o[f + 2], o[f + 3]);
    } else {
        *(float2*)op = make_float2(o[0], o[1]);
    }
}

// ---------------- CSR rowptr build (R3-proven) -----------------------------
__global__ void hist_node_kernel(const int* __restrict__ dst, int* __restrict__ counts, int nE) {
    int e = blockIdx.x * blockDim.x + threadIdx.x;
    if (e < nE) atomicAdd(&counts[dst[e]], 1);
}

__global__ void block_sum_kernel(const int* __restrict__ counts, int* __restrict__ partials, int N) {
    __shared__ int s[256];
    int i = blockIdx.x * 256 + threadIdx.x;
    s[threadIdx.x] = (i < N) ? counts[i] : 0;
    __syncthreads();
    for (int off = 128; off > 0; off >>= 1) {
        if (threadIdx.x < off) s[threadIdx.x] += s[threadIdx.x + off];
        __syncthreads();
    }
    if (threadIdx.x == 0) partials[blockIdx.x] = s[0];
}

__global__ void scan_top_kernel(int* __restrict__ partials, int nb) {
    __shared__ int s[512];
    int t = threadIdx.x;
    s[t] = (t < nb) ? partials[t] : 0;
    __syncthreads();
    for (int off = 1; off < 512; off <<= 1) {
        int v = (t >= off) ? s[t - off] : 0;
        __syncthreads();
        s[t] += v;
        __syncthreads();
    }
    if (t < nb) partials[t] = (t == 0) ? 0 : s[t - 1];
}

__global__ void scan_final_kernel(const int* __restrict__ counts,
                                  const int* __restrict__ partials,
                                  int* __restrict__ rowptr, int N, int nE) {
    __shared__ int s[256];
    int t = threadIdx.x;
    int i = blockIdx.x * 256 + t;
    int v = (i < N) ? counts[i] : 0;
    s[t] = v;
    __syncthreads();
    for (int off = 1; off < 256; off <<= 1) {
        int u = (t >= off) ? s[t - off] : 0;
        __syncthreads();
        s[t] += u;
        __syncthreads();
    }
    if (i < N) rowptr[i] = partials[blockIdx.x] + s[t] - v;
    if (i == 0) rowptr[N] = nE;
}

__global__ void init_gcursor_kernel(const int* __restrict__ rowptr,
                                    int* __restrict__ gcursor, int NB) {
    int b = blockIdx.x * blockDim.x + threadIdx.x;
    if (b < NB) gcursor[b] = rowptr[b * RNODES];
}

// ---------------- phase A: chunked coarse bucketize ------------------------
__global__ void bucketize_chunked_kernel(const int* __restrict__ src,
                                         const int* __restrict__ dst,
                                         int* __restrict__ gcursor,
                                         unsigned int* __restrict__ records,
                                         int nE, int NB) {
    __shared__ int chist[NB_MAX];
    __shared__ int sbase[NB_MAX];
    const int e0 = blockIdx.x * CH;
    const int e1 = min(e0 + CH, nE);

    for (int b = threadIdx.x; b < NB; b += blockDim.x) chist[b] = 0;
    __syncthreads();
    for (int e = e0 + threadIdx.x; e < e1; e += blockDim.x)
        atomicAdd(&chist[dst[e] >> 7], 1);
    __syncthreads();
    for (int b = threadIdx.x; b < NB; b += blockDim.x) {
        int c = chist[b];
        sbase[b] = c ? atomicAdd(&gcursor[b], c) : 0;
        chist[b] = 0;   // reuse as local cursor
    }
    __syncthreads();
    for (int e = e0 + threadIdx.x; e < e1; e += blockDim.x) {
        int d = dst[e];
        int b = d >> 7;
        int l = atomicAdd(&chist[b], 1);
        records[sbase[b] + l] = (unsigned int)src[e] | ((unsigned int)(d & 127) << 17);
    }
}

// ---------------- phase B: fine placement via LDS cursors ------------------
__global__ void place_fine_kernel(const unsigned int* __restrict__ records,
                                  const int* __restrict__ rowptr,
                                  int* __restrict__ srcs_sorted, int N) {
    __shared__ int lcur[RNODES];
    const int b    = blockIdx.x;
    const int base = b * RNODES;
    const int nn   = min(RNODES, N - base);
    if (threadIdx.x < nn) lcur[threadIdx.x] = rowptr[base + threadIdx.x];
    __syncthreads();
    const int beg = rowptr[base];
    const int end = rowptr[base + nn];
    for (int i = beg + threadIdx.x; i < end; i += blockDim.x) {
        unsigned int rec = records[i];
        int pos = atomicAdd(&lcur[rec >> 17], 1);
        srcs_sorted[pos] = (int)(rec & 0x1FFFFu);
    }
}

// ---------------- pull aggregation (R3-proven, unroll 8) -------------------
template <int F, int U, bool SOFTMAX>
__global__ void gather_agg_kernel(const float* __restrict__ t,
                                  const int* __restrict__ rowptr,
                                  const int* __restrict__ srcs,
                                  const float* __restrict__ rootacc,
                                  float* __restrict__ out, int N) {
    int tid = blockIdx.x * blockDim.x + threadIdx.x;
    int n = tid / F;
    if (n >= N) return;
    int f = tid & (F - 1);
    const float* tf = t + f;
    int beg = rowptr[n], end = rowptr[n + 1];
    float sum = 0.0f;
    int e = beg;
    for (; e + U <= end; e += U) {
        int s[U];
        float v[U];
#pragma unroll
        for (int u = 0; u < U; ++u) s[u] = srcs[e + u];
#pragma unroll
        for (int u = 0; u < U; ++u) v[u] = tf[(long)s[u] * F];
#pragma unroll
        for (int u = 0; u < U; ++u) sum += v[u];
    }
    for (; e < end; ++e) sum += tf[(long)srcs[e] * F];

    float v = rootacc[(long)n * F + f] + sum;
    if (!SOFTMAX) {
        out[(long)n * F + f] = v;
    } else {
        float o = __shfl_xor(v, 1, 64);
        float m = fmaxf(v, o);
        float ev = __expf(v - m), eo = __expf(o - m);
        out[(long)n * F + f] = ev / (ev + eo);
    }
}

// ---------------- fallback (R2 atomic path) --------------------------------
template <int F>
__global__ void scatter_kernel(const float* __restrict__ t,
                               const int* __restrict__ src,
                               const int* __restrict__ dst,
                               float* __restrict__ acc, int nE) {
    int tid = blockIdx.x * blockDim.x + threadIdx.x;
    int e = tid / F;
    if (e >= nE) return;
    int f = tid & (F - 1);
    atomicAdd(acc + (long)dst[e] * F + f, t[(long)src[e] * F + f]);
}

__global__ void softmax2_kernel(const float* __restrict__ h, float* __restrict__ out, int N) {
    int n = blockIdx.x * blockDim.x + threadIdx.x;
    if (n >= N) return;
    float a = h[2 * n], b = h[2 * n + 1];
    float m = fmaxf(a, b);
    float ea = __expf(a - m), eb = __expf(b - m);
    float inv = 1.0f / (ea + eb);
    out[2 * n] = ea * inv;
    out[2 * n + 1] = eb * inv;
}

extern "C" void kernel_launch(void* const* d_in, const int* in_sizes, int n_in,
                              void* d_out, int out_size, void* d_ws, size_t ws_size,
                              hipStream_t stream) {
    const float* z      = (const float*)d_in[0];
    const int*   ei     = (const int*)d_in[1];
    const float* Wrel1  = (const float*)d_in[2];
    const float* Wroot1 = (const float*)d_in[3];
    const float* b1     = (const float*)d_in[4];
    const float* Wrel2  = (const float*)d_in[5];
    const float* Wroot2 = (const float*)d_in[6];
    const float* b2     = (const float*)d_in[7];
    const float* Wrel3  = (const float*)d_in[8];
    const float* Wroot3 = (const float*)d_in[9];
    const float* b3     = (const float*)d_in[10];

    const int N  = in_sizes[0] / 64;   // 100000
    const int nE = in_sizes[1] / 2;    // 1600000
    const int* src = ei;
    const int* dst = ei + nE;
    const int NB = (N + RNODES - 1) / RNODES;   // 782

    // Float regions (ping-pong, 12.8 MB each):
    //   regionA: [records (build phase)] -> t1[N*32] -> { t2[N*16] | h2[N*16] }
    //   regionB: h1[N*32] -> t3[N*2]
    float* regionA = (float*)d_ws;
    float* regionB = regionA + (size_t)N * 32;
    float* t1 = regionA;
    float* h1 = regionB;
    float* t2 = regionA;
    float* h2 = regionA + (size_t)N * 16;
    float* t3 = regionB;
    float* h3 = regionB + (size_t)N * 2;
    unsigned int* records = (unsigned int*)regionA;   // transient, pre-t1

    // Int region: ncount[N], rowptr[N+1], partials[512], gcursor[NB_MAX], srcs_sorted[nE]
    int* ibase       = (int*)(regionB + (size_t)N * 32);
    int* ncount      = ibase;
    int* rowptr      = ncount + N;
    int* partials    = rowptr + N + 1;
    int* gcursor     = partials + 512;
    int* srcs_sorted = gcursor + NB_MAX;

    size_t needed = (size_t)N * 64 * sizeof(float)
                  + ((size_t)N + (size_t)N + 1 + 512 + NB_MAX + (size_t)nE) * sizeof(int);

    const int B = 256;
    const int nodeBlocks  = (N + B - 1) / B;
    const int edgeBlocks  = (nE + B - 1) / B;
    const int chunkBlocks = (nE + CH - 1) / CH;
    const dim3 linGrid(nodeBlocks, 2);       // y=0: rel->t, y=1: root+b->acc
    const bool packOK = (N <= (1 << 17)) && (NB <= NB_MAX) && ((size_t)nE * 4 <= (size_t)N * 32 * 4);

    if (ws_size >= needed && packOK) {
        // ---- build: rowptr ----
        hipMemsetAsync(ncount, 0, (size_t)N * sizeof(int), stream);
        hist_node_kernel<<<edgeBlocks, B, 0, stream>>>(dst, ncount, nE);
        block_sum_kernel<<<nodeBlocks, B, 0, stream>>>(ncount, partials, N);
        scan_top_kernel<<<1, 512, 0, stream>>>(partials, nodeBlocks);
        scan_final_kernel<<<nodeBlocks, B, 0, stream>>>(ncount, partials, rowptr, N, nE);
        // ---- build: two-phase placement ----
        init_gcursor_kernel<<<(NB + B - 1) / B, B, 0, stream>>>(rowptr, gcursor, NB);
        bucketize_chunked_kernel<<<chunkBlocks, B, 0, stream>>>(src, dst, gcursor, records, nE, NB);
        place_fine_kernel<<<NB, B, 0, stream>>>(records, rowptr, srcs_sorted, N);

        // ---- Layer 1: 64 -> 32 ----
        linear2_kernel<64, 32, false><<<linGrid, B, 0, stream>>>(z, Wrel1, Wroot1, b1, t1, h1, N);
        gather_agg_kernel<32, 8, false><<<((size_t)N * 32 + B - 1) / B, B, 0, stream>>>(
            t1, rowptr, srcs_sorted, h1, h1, N);

        // ---- Layer 2: 32 -> 16 ----
        linear2_kernel<32, 16, true><<<linGrid, B, 0, stream>>>(h1, Wrel2, Wroot2, b2, t2, h2, N);
        gather_agg_kernel<16, 8, false><<<((size_t)N * 16 + B - 1) / B, B, 0, stream>>>(
            t2, rowptr, srcs_sorted, h2, h2, N);

        // ---- Layer 3: 16 -> 2, softmax fused ----
        linear2_kernel<16, 2, true><<<linGrid, B, 0, stream>>>(h2, Wrel3, Wroot3, b3, t3, h3, N);
        gather_agg_kernel<2, 4, true><<<((size_t)N * 2 + B - 1) / B, B, 0, stream>>>(
            t3, rowptr, srcs_sorted, h3, (float*)d_out, N);
    } else {
        // ---- fallback: R2 atomic-scatter path ----
        linear2_kernel<64, 32, false><<<linGrid, B, 0, stream>>>(z, Wrel1, Wroot1, b1, t1, h1, N);
        scatter_kernel<32><<<((size_t)nE * 32 + B - 1) / B, B, 0, stream>>>(t1, src, dst, h1, nE);
        linear2_kernel<32, 16, true><<<linGrid, B, 0, stream>>>(h1, Wrel2, Wroot2, b2, t2, h2, N);
        scatter_kernel<16><<<((size_t)nE * 16 + B - 1) / B, B, 0, stream>>>(t2, src, dst, h2, nE);
        linear2_kernel<16, 2, true><<<linGrid, B, 0, stream>>>(h2, Wrel3, Wroot3, b3, t3, h3, N);
        scatter_kernel<2><<<((size_t)nE * 2 + B - 1) / B, B, 0, stream>>>(t3, src, dst, h3, nE);
        softmax2_kernel<<<nodeBlocks, B, 0, stream>>>(h3, (float*)d_out, N);
    }
}

// Round 8
// 281.703 us; speedup vs baseline: 1.5708x; 1.2024x over previous
//
#include <hip/hip_runtime.h>
#include <hip/hip_bf16.h>

// 3-layer GraphConv (PyG) + softmax, 100k nodes, 1.6M edges, all f32.
// R2: f32 global atomics ~306G/s scattered -> pull-gather wins.
// R3: per-node CSR scatter: 16x write amplification (128us).
// R4: coarse position-returning cursors: same-address serialization (376us).
// R5: two-phase placement fixed build; transform store-amp found (94us).
// R6: LDS-weight transform regressed (LDS-issue bound, 133us). Reverted.
// R7: linear2 (scalar-path weights, register accs) fixed transform; NEW top =
//     hist_node 65us (1.6M device-scope int atomics, 50MB write traffic).
// R8: kill the per-node hist/scan chain entirely: coarse hist (LDS) + 782-scan
//     + bucketize, then place_merge computes per-node hist+scan+rowptr INSIDE
//     each bucket with LDS atomics and places records. 5 kernels -> 0 global
//     atomics on the node histogram.

#define RNODES 128
#define NB_MAX 1024
#define CH 8192            // edges per bucketize chunk

// ---------------- linear: out = act(x) @ W (+ bias for root task) ----------
template <int Fin, int Fout, bool RELU>
__global__ void linear2_kernel(const float* __restrict__ x,
                               const float* __restrict__ Wrel,
                               const float* __restrict__ Wroot,
                               const float* __restrict__ bias,
                               float* __restrict__ t,
                               float* __restrict__ acc, int N) {
    const bool rootTask = (blockIdx.y != 0);
    const float* __restrict__ W = rootTask ? Wroot : Wrel;
    float* __restrict__ outp    = rootTask ? acc : t;

    int n = blockIdx.x * blockDim.x + threadIdx.x;
    if (n >= N) return;

    float o[Fout];
#pragma unroll
    for (int f = 0; f < Fout; ++f) o[f] = 0.f;

    const float* xr = x + (size_t)n * Fin;
    for (int k0 = 0; k0 < Fin; k0 += 16) {
#pragma unroll
        for (int k = 0; k < 16; k += 4) {
            float4 v = *(const float4*)(xr + k0 + k);
            if (RELU) {
                v.x = fmaxf(v.x, 0.f); v.y = fmaxf(v.y, 0.f);
                v.z = fmaxf(v.z, 0.f); v.w = fmaxf(v.w, 0.f);
            }
            const float xv[4] = {v.x, v.y, v.z, v.w};
#pragma unroll
            for (int kk = 0; kk < 4; ++kk) {
                const float* wr = W + (size_t)(k0 + k + kk) * Fout;
#pragma unroll
                for (int f = 0; f < Fout; ++f)
                    o[f] = fmaf(xv[kk], wr[f], o[f]);
            }
        }
    }
    if (rootTask) {
#pragma unroll
        for (int f = 0; f < Fout; ++f) o[f] += bias[f];
    }
    float* op = outp + (size_t)n * Fout;
    if constexpr (Fout >= 4) {
#pragma unroll
        for (int f = 0; f < Fout; f += 4)
            *(float4*)(op + f) = make_float4(o[f], o[f + 1], o[f + 2], o[f + 3]);
    } else {
        *(float2*)op = make_float2(o[0], o[1]);
    }
}

// ---------------- coarse hist (LDS, batched merge) -------------------------
__global__ void hist_coarse_kernel(const int* __restrict__ dst,
                                   int* __restrict__ gcount, int nE, int NB) {
    __shared__ int h[NB_MAX];
    for (int i = threadIdx.x; i < NB; i += blockDim.x) h[i] = 0;
    __syncthreads();
    int stride = gridDim.x * blockDim.x;
    for (int e = blockIdx.x * blockDim.x + threadIdx.x; e < nE; e += stride)
        atomicAdd(&h[dst[e] >> 7], 1);
    __syncthreads();
    for (int i = threadIdx.x; i < NB; i += blockDim.x)
        if (h[i]) atomicAdd(&gcount[i], h[i]);   // no-return: pipelined
}

// single block: exclusive scan over NB<=1024 coarse counts -> bptr, gcursor.
__global__ void scan_buckets_kernel(const int* __restrict__ gcount,
                                    int* __restrict__ bptr,
                                    int* __restrict__ gcursor, int NB, int nE) {
    __shared__ int s[NB_MAX];
    int t = threadIdx.x;
    int own = (t < NB) ? gcount[t] : 0;
    s[t] = own;
    __syncthreads();
    for (int off = 1; off < NB_MAX; off <<= 1) {
        int v = (t >= off) ? s[t - off] : 0;
        __syncthreads();
        s[t] += v;
        __syncthreads();
    }
    if (t < NB) {
        int ex = s[t] - own;
        bptr[t]    = ex;
        gcursor[t] = ex;
    }
    if (t == 0) bptr[NB] = nE;
}

// ---------------- phase A: chunked coarse bucketize ------------------------
__global__ void bucketize_chunked_kernel(const int* __restrict__ src,
                                         const int* __restrict__ dst,
                                         int* __restrict__ gcursor,
                                         unsigned int* __restrict__ records,
                                         int nE, int NB) {
    __shared__ int chist[NB_MAX];
    __shared__ int sbase[NB_MAX];
    const int e0 = blockIdx.x * CH;
    const int e1 = min(e0 + CH, nE);

    for (int b = threadIdx.x; b < NB; b += blockDim.x) chist[b] = 0;
    __syncthreads();
    for (int e = e0 + threadIdx.x; e < e1; e += blockDim.x)
        atomicAdd(&chist[dst[e] >> 7], 1);
    __syncthreads();
    for (int b = threadIdx.x; b < NB; b += blockDim.x) {
        int c = chist[b];
        sbase[b] = c ? atomicAdd(&gcursor[b], c) : 0;
        chist[b] = 0;   // reuse as local cursor
    }
    __syncthreads();
    for (int e = e0 + threadIdx.x; e < e1; e += blockDim.x) {
        int d = dst[e];
        int b = d >> 7;
        int l = atomicAdd(&chist[b], 1);
        records[sbase[b] + l] = (unsigned int)src[e] | ((unsigned int)(d & 127) << 17);
    }
}

// ---------------- phase B: per-bucket hist + scan + rowptr + place ---------
__global__ void place_merge_kernel(const unsigned int* __restrict__ records,
                                   const int* __restrict__ bptr,
                                   int* __restrict__ rowptr,
                                   int* __restrict__ srcs_sorted,
                                   int N, int nE, int NB) {
    __shared__ int hist[RNODES];
    __shared__ int s[RNODES];
    __shared__ int lcur[RNODES];
    const int b    = blockIdx.x;
    const int base = b * RNODES;
    const int nn   = min(RNODES, N - base);
    const int beg  = bptr[b], end = bptr[b + 1];
    const int t    = threadIdx.x;

    if (t < RNODES) hist[t] = 0;
    __syncthreads();
    for (int i = beg + t; i < end; i += blockDim.x)
        atomicAdd(&hist[records[i] >> 17], 1);
    __syncthreads();

    // exclusive scan over 128 counts (Hillis-Steele, predicated)
    if (t < RNODES) s[t] = hist[t];
    __syncthreads();
    for (int off = 1; off < RNODES; off <<= 1) {
        int v = (t < RNODES && t >= off) ? s[t - off] : 0;
        __syncthreads();
        if (t < RNODES && t >= off) s[t] += v;
        __syncthreads();
    }
    if (t < nn) {
        int ex = beg + s[t] - hist[t];
        rowptr[base + t] = ex;
        lcur[t] = ex;
    }
    if (b == NB - 1 && t == 0) rowptr[N] = nE;
    __syncthreads();

    for (int i = beg + t; i < end; i += blockDim.x) {
        unsigned int rec = records[i];
        int pos = atomicAdd(&lcur[rec >> 17], 1);
        srcs_sorted[pos] = (int)(rec & 0x1FFFFu);
    }
}

// ---------------- pull aggregation (R3-proven, unroll 8) -------------------
template <int F, int U, bool SOFTMAX>
__global__ void gather_agg_kernel(const float* __restrict__ t,
                                  const int* __restrict__ rowptr,
                                  const int* __restrict__ srcs,
                                  const float* __restrict__ rootacc,
                                  float* __restrict__ out, int N) {
    int tid = blockIdx.x * blockDim.x + threadIdx.x;
    int n = tid / F;
    if (n >= N) return;
    int f = tid & (F - 1);
    const float* tf = t + f;
    int beg = rowptr[n], end = rowptr[n + 1];
    float sum = 0.0f;
    int e = beg;
    for (; e + U <= end; e += U) {
        int s[U];
        float v[U];
#pragma unroll
        for (int u = 0; u < U; ++u) s[u] = srcs[e + u];
#pragma unroll
        for (int u = 0; u < U; ++u) v[u] = tf[(long)s[u] * F];
#pragma unroll
        for (int u = 0; u < U; ++u) sum += v[u];
    }
    for (; e < end; ++e) sum += tf[(long)srcs[e] * F];

    float v = rootacc[(long)n * F + f] + sum;
    if (!SOFTMAX) {
        out[(long)n * F + f] = v;
    } else {
        float o = __shfl_xor(v, 1, 64);
        float m = fmaxf(v, o);
        float ev = __expf(v - m), eo = __expf(o - m);
        out[(long)n * F + f] = ev / (ev + eo);
    }
}

// ---------------- fallback (R2 atomic path) --------------------------------
template <int F>
__global__ void scatter_kernel(const float* __restrict__ t,
                               const int* __restrict__ src,
                               const int* __restrict__ dst,
                               float* __restrict__ acc, int nE) {
    int tid = blockIdx.x * blockDim.x + threadIdx.x;
    int e = tid / F;
    if (e >= nE) return;
    int f = tid & (F - 1);
    atomicAdd(acc + (long)dst[e] * F + f, t[(long)src[e] * F + f]);
}

__global__ void softmax2_kernel(const float* __restrict__ h, float* __restrict__ out, int N) {
    int n = blockIdx.x * blockDim.x + threadIdx.x;
    if (n >= N) return;
    float a = h[2 * n], b = h[2 * n + 1];
    float m = fmaxf(a, b);
    float ea = __expf(a - m), eb = __expf(b - m);
    float inv = 1.0f / (ea + eb);
    out[2 * n] = ea * inv;
    out[2 * n + 1] = eb * inv;
}

extern "C" void kernel_launch(void* const* d_in, const int* in_sizes, int n_in,
                              void* d_out, int out_size, void* d_ws, size_t ws_size,
                              hipStream_t stream) {
    const float* z      = (const float*)d_in[0];
    const int*   ei     = (const int*)d_in[1];
    const float* Wrel1  = (const float*)d_in[2];
    const float* Wroot1 = (const float*)d_in[3];
    const float* b1     = (const float*)d_in[4];
    const float* Wrel2  = (const float*)d_in[5];
    const float* Wroot2 = (const float*)d_in[6];
    const float* b2     = (const float*)d_in[7];
    const float* Wrel3  = (const float*)d_in[8];
    const float* Wroot3 = (const float*)d_in[9];
    const float* b3     = (const float*)d_in[10];

    const int N  = in_sizes[0] / 64;   // 100000
    const int nE = in_sizes[1] / 2;    // 1600000
    const int* src = ei;
    const int* dst = ei + nE;
    const int NB = (N + RNODES - 1) / RNODES;   // 782

    // Float regions (ping-pong, 12.8 MB each):
    //   regionA: [records (build phase)] -> t1[N*32] -> { t2[N*16] | h2[N*16] }
    //   regionB: h1[N*32] -> t3[N*2]
    float* regionA = (float*)d_ws;
    float* regionB = regionA + (size_t)N * 32;
    float* t1 = regionA;
    float* h1 = regionB;
    float* t2 = regionA;
    float* h2 = regionA + (size_t)N * 16;
    float* t3 = regionB;
    float* h3 = regionB + (size_t)N * 2;
    unsigned int* records = (unsigned int*)regionA;   // transient, pre-t1

    // Int region: gcount[NB_MAX], bptr[NB_MAX+1], gcursor[NB_MAX],
    //             rowptr[N+1], srcs_sorted[nE]
    int* ibase       = (int*)(regionB + (size_t)N * 32);
    int* gcount      = ibase;
    int* bptr        = gcount + NB_MAX;
    int* gcursor     = bptr + NB_MAX + 1;
    int* rowptr      = gcursor + NB_MAX;
    int* srcs_sorted = rowptr + N + 1;

    size_t needed = (size_t)N * 64 * sizeof(float)
                  + ((size_t)3 * NB_MAX + 1 + (size_t)N + 1 + (size_t)nE) * sizeof(int);

    const int B = 256;
    const int nodeBlocks  = (N + B - 1) / B;
    const int chunkBlocks = (nE + CH - 1) / CH;
    const dim3 linGrid(nodeBlocks, 2);       // y=0: rel->t, y=1: root+b->acc
    const bool packOK = (N <= (1 << 17)) && (NB <= NB_MAX) && ((size_t)nE * 4 <= (size_t)N * 32 * 4);

    if (ws_size >= needed && packOK) {
        // ---- build: coarse hist -> scan -> bucketize -> place(+rowptr) ----
        hipMemsetAsync(gcount, 0, (size_t)NB * sizeof(int), stream);
        hist_coarse_kernel<<<256, B, 0, stream>>>(dst, gcount, nE, NB);
        scan_buckets_kernel<<<1, NB_MAX, 0, stream>>>(gcount, bptr, gcursor, NB, nE);
        bucketize_chunked_kernel<<<chunkBlocks, B, 0, stream>>>(src, dst, gcursor, records, nE, NB);
        place_merge_kernel<<<NB, B, 0, stream>>>(records, bptr, rowptr, srcs_sorted, N, nE, NB);

        // ---- Layer 1: 64 -> 32 ----
        linear2_kernel<64, 32, false><<<linGrid, B, 0, stream>>>(z, Wrel1, Wroot1, b1, t1, h1, N);
        gather_agg_kernel<32, 8, false><<<((size_t)N * 32 + B - 1) / B, B, 0, stream>>>(
            t1, rowptr, srcs_sorted, h1, h1, N);

        // ---- Layer 2: 32 -> 16 ----
        linear2_kernel<32, 16, true><<<linGrid, B, 0, stream>>>(h1, Wrel2, Wroot2, b2, t2, h2, N);
        gather_agg_kernel<16, 8, false><<<((size_t)N * 16 + B - 1) / B, B, 0, stream>>>(
            t2, rowptr, srcs_sorted, h2, h2, N);

        // ---- Layer 3: 16 -> 2, softmax fused ----
        linear2_kernel<16, 2, true><<<linGrid, B, 0, stream>>>(h2, Wrel3, Wroot3, b3, t3, h3, N);
        gather_agg_kernel<2, 4, true><<<((size_t)N * 2 + B - 1) / B, B, 0, stream>>>(
            t3, rowptr, srcs_sorted, h3, (float*)d_out, N);
    } else {
        // ---- fallback: R2 atomic-scatter path ----
        linear2_kernel<64, 32, false><<<linGrid, B, 0, stream>>>(z, Wrel1, Wroot1, b1, t1, h1, N);
        scatter_kernel<32><<<((size_t)nE * 32 + B - 1) / B, B, 0, stream>>>(t1, src, dst, h1, nE);
        linear2_kernel<32, 16, true><<<linGrid, B, 0, stream>>>(h1, Wrel2, Wroot2, b2, t2, h2, N);
        scatter_kernel<16><<<((size_t)nE * 16 + B - 1) / B, B, 0, stream>>>(t2, src, dst, h2, nE);
        linear2_kernel<16, 2, true><<<linGrid, B, 0, stream>>>(h2, Wrel3, Wroot3, b3, t3, h3, N);
        scatter_kernel<2><<<((size_t)nE * 2 + B - 1) / B, B, 0, stream>>>(t3, src, dst, h3, nE);
        softmax2_kernel<<<nodeBlocks, B, 0, stream>>>(h3, (float*)d_out, N);
    }
}

// Round 9
// 253.043 us; speedup vs baseline: 1.7487x; 1.1133x over previous
//
#include <hip/hip_runtime.h>
#include <hip/hip_bf16.h>

// 3-layer GraphConv (PyG) + softmax, 100k nodes, 1.6M edges, all f32.
// R2: f32 global atomics ~306G/s scattered -> pull-gather wins.
// R3: per-node CSR scatter: 16x write amplification (128us).
// R4: coarse position-returning cursors: same-address serialization (376us).
// R5: two-phase placement fixed build; transform store-amp found (94us).
// R6: LDS-weight transform regressed (LDS-issue bound, 133us). Reverted.
// R7: linear2 (scalar-path weights, register accs) fixed transform.
// R8: coarse-first build killed hist_node; bucketize_chunked top at 49us:
//     occupancy 5% (196 blocks x 256thr) + 196-deep reservation atomic chains.
// R9: fully deterministic placement: per-chunk hist table -> column prefix
//     scan -> bucket scan -> placement with precomputed (chunk,bucket) bases.
//     ZERO global atomics in build; 1024-thr blocks for occupancy.

#define RNODES 128
#define NB_MAX 1024
#define CH 8192            // edges per chunk
#define CMAX 256           // max chunks (scan_chunkhist holds one chunk/thread)

// ---------------- linear: out = act(x) @ W (+ bias for root task) ----------
template <int Fin, int Fout, bool RELU>
__global__ void linear2_kernel(const float* __restrict__ x,
                               const float* __restrict__ Wrel,
                               const float* __restrict__ Wroot,
                               const float* __restrict__ bias,
                               float* __restrict__ t,
                               float* __restrict__ acc, int N) {
    const bool rootTask = (blockIdx.y != 0);
    const float* __restrict__ W = rootTask ? Wroot : Wrel;
    float* __restrict__ outp    = rootTask ? acc : t;

    int n = blockIdx.x * blockDim.x + threadIdx.x;
    if (n >= N) return;

    float o[Fout];
#pragma unroll
    for (int f = 0; f < Fout; ++f) o[f] = 0.f;

    const float* xr = x + (size_t)n * Fin;
    for (int k0 = 0; k0 < Fin; k0 += 16) {
#pragma unroll
        for (int k = 0; k < 16; k += 4) {
            float4 v = *(const float4*)(xr + k0 + k);
            if (RELU) {
                v.x = fmaxf(v.x, 0.f); v.y = fmaxf(v.y, 0.f);
                v.z = fmaxf(v.z, 0.f); v.w = fmaxf(v.w, 0.f);
            }
            const float xv[4] = {v.x, v.y, v.z, v.w};
#pragma unroll
            for (int kk = 0; kk < 4; ++kk) {
                const float* wr = W + (size_t)(k0 + k + kk) * Fout;
#pragma unroll
                for (int f = 0; f < Fout; ++f)
                    o[f] = fmaf(xv[kk], wr[f], o[f]);
            }
        }
    }
    if (rootTask) {
#pragma unroll
        for (int f = 0; f < Fout; ++f) o[f] += bias[f];
    }
    float* op = outp + (size_t)n * Fout;
    if constexpr (Fout >= 4) {
#pragma unroll
        for (int f = 0; f < Fout; f += 4)
            *(float4*)(op + f) = make_float4(o[f], o[f + 1], o[f + 2], o[f + 3]);
    } else {
        *(float2*)op = make_float2(o[0], o[1]);
    }
}

// ---------------- build step 1: per-chunk LDS histogram --------------------
__global__ void hist_chunked_kernel(const int* __restrict__ dst,
                                    int* __restrict__ chunkhist,
                                    int nE, int NB) {
    __shared__ int h[NB_MAX];
    const int c  = blockIdx.x;
    const int e0 = c * CH, e1 = min(e0 + CH, nE);
    for (int b = threadIdx.x; b < NB; b += blockDim.x) h[b] = 0;
    __syncthreads();
    for (int e = e0 + threadIdx.x; e < e1; e += blockDim.x)
        atomicAdd(&h[dst[e] >> 7], 1);
    __syncthreads();
    for (int b = threadIdx.x; b < NB; b += blockDim.x)
        chunkhist[(size_t)c * NB + b] = h[b];          // contiguous row flush
}

// ---------------- build step 2: column scan (per bucket over chunks) -------
// Block b: exclusive prefix over chunkhist[:, b] (written back) + gtotal[b].
__global__ void scan_chunkhist_kernel(int* __restrict__ chunkhist,
                                      int* __restrict__ gtotal,
                                      int C, int NB) {
    __shared__ int s[CMAX];
    const int b = blockIdx.x;
    const int t = threadIdx.x;
    int v = (t < C) ? chunkhist[(size_t)t * NB + b] : 0;
    s[t] = v;
    __syncthreads();
    for (int off = 1; off < CMAX; off <<= 1) {
        int u = (t >= off) ? s[t - off] : 0;
        __syncthreads();
        s[t] += u;
        __syncthreads();
    }
    if (t < C) chunkhist[(size_t)t * NB + b] = s[t] - v;   // exclusive
    if (t == CMAX - 1) gtotal[b] = s[t];                   // inclusive total
}

// ---------------- build step 3: bucket scan (single block) -----------------
__global__ void scan_buckets_kernel(const int* __restrict__ gtotal,
                                    int* __restrict__ bptr, int NB, int nE) {
    __shared__ int s[NB_MAX];
    int t = threadIdx.x;
    int own = (t < NB) ? gtotal[t] : 0;
    s[t] = own;
    __syncthreads();
    for (int off = 1; off < NB_MAX; off <<= 1) {
        int v = (t >= off) ? s[t - off] : 0;
        __syncthreads();
        s[t] += v;
        __syncthreads();
    }
    if (t < NB) bptr[t] = s[t] - own;
    if (t == 0) bptr[NB] = nE;
}

// ---------------- build step 4: deterministic placement --------------------
__global__ void bucketize_det_kernel(const int* __restrict__ src,
                                     const int* __restrict__ dst,
                                     const int* __restrict__ chunkpre,
                                     const int* __restrict__ bptr,
                                     unsigned int* __restrict__ records,
                                     int nE, int NB) {
    __shared__ int lcur[NB_MAX];
    const int c  = blockIdx.x;
    const int e0 = c * CH, e1 = min(e0 + CH, nE);
    for (int b = threadIdx.x; b < NB; b += blockDim.x)
        lcur[b] = bptr[b] + chunkpre[(size_t)c * NB + b];
    __syncthreads();
    for (int e = e0 + threadIdx.x; e < e1; e += blockDim.x) {
        int d = dst[e];
        int b = d >> 7;
        int pos = atomicAdd(&lcur[b], 1);                  // LDS-only atomic
        records[pos] = (unsigned int)src[e] | ((unsigned int)(d & 127) << 17);
    }
}

// ---------------- build step 5: per-bucket hist+scan+rowptr+place ----------
__global__ void place_merge_kernel(const unsigned int* __restrict__ records,
                                   const int* __restrict__ bptr,
                                   int* __restrict__ rowptr,
                                   int* __restrict__ srcs_sorted,
                                   int N, int nE, int NB) {
    __shared__ int hist[RNODES];
    __shared__ int s[RNODES];
    __shared__ int lcur[RNODES];
    const int b    = blockIdx.x;
    const int base = b * RNODES;
    const int nn   = min(RNODES, N - base);
    const int beg  = bptr[b], end = bptr[b + 1];
    const int t    = threadIdx.x;

    if (t < RNODES) hist[t] = 0;
    __syncthreads();
    for (int i = beg + t; i < end; i += blockDim.x)
        atomicAdd(&hist[records[i] >> 17], 1);
    __syncthreads();

    if (t < RNODES) s[t] = hist[t];
    __syncthreads();
    for (int off = 1; off < RNODES; off <<= 1) {
        int v = (t < RNODES && t >= off) ? s[t - off] : 0;
        __syncthreads();
        if (t < RNODES && t >= off) s[t] += v;
        __syncthreads();
    }
    if (t < nn) {
        int ex = beg + s[t] - hist[t];
        rowptr[base + t] = ex;
        lcur[t] = ex;
    }
    if (b == NB - 1 && t == 0) rowptr[N] = nE;
    __syncthreads();

    for (int i = beg + t; i < end; i += blockDim.x) {
        unsigned int rec = records[i];
        int pos = atomicAdd(&lcur[rec >> 17], 1);
        srcs_sorted[pos] = (int)(rec & 0x1FFFFu);
    }
}

// ---------------- pull aggregation (R3-proven, unroll 8) -------------------
template <int F, int U, bool SOFTMAX>
__global__ void gather_agg_kernel(const float* __restrict__ t,
                                  const int* __restrict__ rowptr,
                                  const int* __restrict__ srcs,
                                  const float* __restrict__ rootacc,
                                  float* __restrict__ out, int N) {
    int tid = blockIdx.x * blockDim.x + threadIdx.x;
    int n = tid / F;
    if (n >= N) return;
    int f = tid & (F - 1);
    const float* tf = t + f;
    int beg = rowptr[n], end = rowptr[n + 1];
    float sum = 0.0f;
    int e = beg;
    for (; e + U <= end; e += U) {
        int s[U];
        float v[U];
#pragma unroll
        for (int u = 0; u < U; ++u) s[u] = srcs[e + u];
#pragma unroll
        for (int u = 0; u < U; ++u) v[u] = tf[(long)s[u] * F];
#pragma unroll
        for (int u = 0; u < U; ++u) sum += v[u];
    }
    for (; e < end; ++e) sum += tf[(long)srcs[e] * F];

    float v = rootacc[(long)n * F + f] + sum;
    if (!SOFTMAX) {
        out[(long)n * F + f] = v;
    } else {
        float o = __shfl_xor(v, 1, 64);
        float m = fmaxf(v, o);
        float ev = __expf(v - m), eo = __expf(o - m);
        out[(long)n * F + f] = ev / (ev + eo);
    }
}

// ---------------- fallback (R2 atomic path) --------------------------------
template <int F>
__global__ void scatter_kernel(const float* __restrict__ t,
                               const int* __restrict__ src,
                               const int* __restrict__ dst,
                               float* __restrict__ acc, int nE) {
    int tid = blockIdx.x * blockDim.x + threadIdx.x;
    int e = tid / F;
    if (e >= nE) return;
    int f = tid & (F - 1);
    atomicAdd(acc + (long)dst[e] * F + f, t[(long)src[e] * F + f]);
}

__global__ void softmax2_kernel(const float* __restrict__ h, float* __restrict__ out, int N) {
    int n = blockIdx.x * blockDim.x + threadIdx.x;
    if (n >= N) return;
    float a = h[2 * n], b = h[2 * n + 1];
    float m = fmaxf(a, b);
    float ea = __expf(a - m), eb = __expf(b - m);
    float inv = 1.0f / (ea + eb);
    out[2 * n] = ea * inv;
    out[2 * n + 1] = eb * inv;
}

extern "C" void kernel_launch(void* const* d_in, const int* in_sizes, int n_in,
                              void* d_out, int out_size, void* d_ws, size_t ws_size,
                              hipStream_t stream) {
    const float* z      = (const float*)d_in[0];
    const int*   ei     = (const int*)d_in[1];
    const float* Wrel1  = (const float*)d_in[2];
    const float* Wroot1 = (const float*)d_in[3];
    const float* b1     = (const float*)d_in[4];
    const float* Wrel2  = (const float*)d_in[5];
    const float* Wroot2 = (const float*)d_in[6];
    const float* b2     = (const float*)d_in[7];
    const float* Wrel3  = (const float*)d_in[8];
    const float* Wroot3 = (const float*)d_in[9];
    const float* b3     = (const float*)d_in[10];

    const int N  = in_sizes[0] / 64;   // 100000
    const int nE = in_sizes[1] / 2;    // 1600000
    const int* src = ei;
    const int* dst = ei + nE;
    const int NB = (N + RNODES - 1) / RNODES;   // 782
    const int C  = (nE + CH - 1) / CH;          // 196 chunks

    // Float regions (ping-pong, 12.8 MB each):
    //   regionA: [records (build)] -> t1[N*32] -> { t2[N*16] | h2[N*16] }
    //   regionB: [chunkhist/gtotal/bptr (build)] -> h1[N*32] -> t3[N*2]
    float* regionA = (float*)d_ws;
    float* regionB = regionA + (size_t)N * 32;
    float* t1 = regionA;
    float* h1 = regionB;
    float* t2 = regionA;
    float* h2 = regionA + (size_t)N * 16;
    float* t3 = regionB;
    float* h3 = regionB + (size_t)N * 2;
    unsigned int* records = (unsigned int*)regionA;   // transient, pre-t1

    // Build tables in regionB (dead until h1 is written in layer 1):
    int* chunkhist = (int*)regionB;                   // [C][NB], C<=CMAX
    int* gtotal    = chunkhist + (size_t)CMAX * NB_MAX;
    int* bptr      = gtotal + NB_MAX;                 // [NB+1]
    // Persistent int region: rowptr[N+1], srcs_sorted[nE]
    int* ibase       = (int*)(regionB + (size_t)N * 32);
    int* rowptr      = ibase;
    int* srcs_sorted = rowptr + N + 1;

    size_t needed = (size_t)N * 64 * sizeof(float)
                  + ((size_t)N + 1 + (size_t)nE) * sizeof(int);
    size_t buildNeed = ((size_t)CMAX * NB_MAX + NB_MAX + NB_MAX + 1) * sizeof(int);

    const int B = 256;
    const int nodeBlocks = (N + B - 1) / B;
    const dim3 linGrid(nodeBlocks, 2);       // y=0: rel->t, y=1: root+b->acc
    const bool packOK = (N <= (1 << 17)) && (NB <= NB_MAX) && (C <= CMAX)
                      && ((size_t)nE * 4 <= (size_t)N * 32 * 4)
                      && (buildNeed <= (size_t)N * 32 * 4);

    if (ws_size >= needed && packOK) {
        // ---- build: zero-global-atomic deterministic CSR ----
        hist_chunked_kernel<<<C, 1024, 0, stream>>>(dst, chunkhist, nE, NB);
        scan_chunkhist_kernel<<<NB, CMAX, 0, stream>>>(chunkhist, gtotal, C, NB);
        scan_buckets_kernel<<<1, NB_MAX, 0, stream>>>(gtotal, bptr, NB, nE);
        bucketize_det_kernel<<<C, 1024, 0, stream>>>(src, dst, chunkhist, bptr, records, nE, NB);
        place_merge_kernel<<<NB, B, 0, stream>>>(records, bptr, rowptr, srcs_sorted, N, nE, NB);

        // ---- Layer 1: 64 -> 32 ----
        linear2_kernel<64, 32, false><<<linGrid, B, 0, stream>>>(z, Wrel1, Wroot1, b1, t1, h1, N);
        gather_agg_kernel<32, 8, false><<<((size_t)N * 32 + B - 1) / B, B, 0, stream>>>(
            t1, rowptr, srcs_sorted, h1, h1, N);

        // ---- Layer 2: 32 -> 16 ----
        linear2_kernel<32, 16, true><<<linGrid, B, 0, stream>>>(h1, Wrel2, Wroot2, b2, t2, h2, N);
        gather_agg_kernel<16, 8, false><<<((size_t)N * 16 + B - 1) / B, B, 0, stream>>>(
            t2, rowptr, srcs_sorted, h2, h2, N);

        // ---- Layer 3: 16 -> 2, softmax fused ----
        linear2_kernel<16, 2, true><<<linGrid, B, 0, stream>>>(h2, Wrel3, Wroot3, b3, t3, h3, N);
        gather_agg_kernel<2, 4, true><<<((size_t)N * 2 + B - 1) / B, B, 0, stream>>>(
            t3, rowptr, srcs_sorted, h3, (float*)d_out, N);
    } else {
        // ---- fallback: R2 atomic-scatter path ----
        linear2_kernel<64, 32, false><<<linGrid, B, 0, stream>>>(z, Wrel1, Wroot1, b1, t1, h1, N);
        scatter_kernel<32><<<((size_t)nE * 32 + B - 1) / B, B, 0, stream>>>(t1, src, dst, h1, nE);
        linear2_kernel<32, 16, true><<<linGrid, B, 0, stream>>>(h1, Wrel2, Wroot2, b2, t2, h2, N);
        scatter_kernel<16><<<((size_t)nE * 16 + B - 1) / B, B, 0, stream>>>(t2, src, dst, h2, nE);
        linear2_kernel<16, 2, true><<<linGrid, B, 0, stream>>>(h2, Wrel3, Wroot3, b3, t3, h3, N);
        scatter_kernel<2><<<((size_t)nE * 2 + B - 1) / B, B, 0, stream>>>(t3, src, dst, h3, nE);
        softmax2_kernel<<<nodeBlocks, B, 0, stream>>>(h3, (float*)d_out, N);
    }
}

// Round 10
// 248.719 us; speedup vs baseline: 1.7791x; 1.0174x over previous
//
#include <hip/hip_runtime.h>
#include <hip/hip_bf16.h>

// 3-layer GraphConv (PyG) + softmax, 100k nodes, 1.6M edges, all f32.
// R2: f32 global atomics ~306G/s scattered -> pull-gather wins.
// R3: per-node CSR scatter: 16x write amplification (128us).
// R4: coarse position-returning cursors: same-address serialization (376us).
// R5: two-phase placement fixed build; transform store-amp found (94us).
// R6: LDS-weight transform regressed (LDS-issue bound, 133us). Reverted.
// R7: linear2 (scalar-path weights, register accs) fixed transform.
// R8: coarse-first build killed hist_node; reservation chains next (49us).
// R9: fully deterministic build (zero global atomics). gather32 = 44.5us,
//     MLP-limited (0.5MB in flight vs 2.3MB BWxlatency need), occupancy 62%.
// R10: staged gather unroll (16/4/1) for 2x lines in flight; build chunks
//      4096 (391 blocks) + 512-thr blocks for occupancy. No structural change.

#define RNODES 128
#define NB_MAX 1024
#define CH 4096            // edges per chunk
#define CMAX 512           // max chunks (scan_chunkhist: one chunk/thread)

// ---------------- linear: out = act(x) @ W (+ bias for root task) ----------
template <int Fin, int Fout, bool RELU>
__global__ void linear2_kernel(const float* __restrict__ x,
                               const float* __restrict__ Wrel,
                               const float* __restrict__ Wroot,
                               const float* __restrict__ bias,
                               float* __restrict__ t,
                               float* __restrict__ acc, int N) {
    const bool rootTask = (blockIdx.y != 0);
    const float* __restrict__ W = rootTask ? Wroot : Wrel;
    float* __restrict__ outp    = rootTask ? acc : t;

    int n = blockIdx.x * blockDim.x + threadIdx.x;
    if (n >= N) return;

    float o[Fout];
#pragma unroll
    for (int f = 0; f < Fout; ++f) o[f] = 0.f;

    const float* xr = x + (size_t)n * Fin;
    for (int k0 = 0; k0 < Fin; k0 += 16) {
#pragma unroll
        for (int k = 0; k < 16; k += 4) {
            float4 v = *(const float4*)(xr + k0 + k);
            if (RELU) {
                v.x = fmaxf(v.x, 0.f); v.y = fmaxf(v.y, 0.f);
                v.z = fmaxf(v.z, 0.f); v.w = fmaxf(v.w, 0.f);
            }
            const float xv[4] = {v.x, v.y, v.z, v.w};
#pragma unroll
            for (int kk = 0; kk < 4; ++kk) {
                const float* wr = W + (size_t)(k0 + k + kk) * Fout;
#pragma unroll
                for (int f = 0; f < Fout; ++f)
                    o[f] = fmaf(xv[kk], wr[f], o[f]);
            }
        }
    }
    if (rootTask) {
#pragma unroll
        for (int f = 0; f < Fout; ++f) o[f] += bias[f];
    }
    float* op = outp + (size_t)n * Fout;
    if constexpr (Fout >= 4) {
#pragma unroll
        for (int f = 0; f < Fout; f += 4)
            *(float4*)(op + f) = make_float4(o[f], o[f + 1], o[f + 2], o[f + 3]);
    } else {
        *(float2*)op = make_float2(o[0], o[1]);
    }
}

// ---------------- build step 1: per-chunk LDS histogram --------------------
__global__ void hist_chunked_kernel(const int* __restrict__ dst,
                                    int* __restrict__ chunkhist,
                                    int nE, int NB) {
    __shared__ int h[NB_MAX];
    const int c  = blockIdx.x;
    const int e0 = c * CH, e1 = min(e0 + CH, nE);
    for (int b = threadIdx.x; b < NB; b += blockDim.x) h[b] = 0;
    __syncthreads();
    for (int e = e0 + threadIdx.x; e < e1; e += blockDim.x)
        atomicAdd(&h[dst[e] >> 7], 1);
    __syncthreads();
    for (int b = threadIdx.x; b < NB; b += blockDim.x)
        chunkhist[(size_t)c * NB + b] = h[b];          // contiguous row flush
}

// ---------------- build step 2: column scan (per bucket over chunks) -------
__global__ void scan_chunkhist_kernel(int* __restrict__ chunkhist,
                                      int* __restrict__ gtotal,
                                      int C, int NB) {
    __shared__ int s[CMAX];
    const int b = blockIdx.x;
    const int t = threadIdx.x;
    int v = (t < C) ? chunkhist[(size_t)t * NB + b] : 0;
    s[t] = v;
    __syncthreads();
    for (int off = 1; off < CMAX; off <<= 1) {
        int u = (t >= off) ? s[t - off] : 0;
        __syncthreads();
        s[t] += u;
        __syncthreads();
    }
    if (t < C) chunkhist[(size_t)t * NB + b] = s[t] - v;   // exclusive
    if (t == CMAX - 1) gtotal[b] = s[t];                   // inclusive total
}

// ---------------- build step 3: bucket scan (single block) -----------------
__global__ void scan_buckets_kernel(const int* __restrict__ gtotal,
                                    int* __restrict__ bptr, int NB, int nE) {
    __shared__ int s[NB_MAX];
    int t = threadIdx.x;
    int own = (t < NB) ? gtotal[t] : 0;
    s[t] = own;
    __syncthreads();
    for (int off = 1; off < NB_MAX; off <<= 1) {
        int v = (t >= off) ? s[t - off] : 0;
        __syncthreads();
        s[t] += v;
        __syncthreads();
    }
    if (t < NB) bptr[t] = s[t] - own;
    if (t == 0) bptr[NB] = nE;
}

// ---------------- build step 4: deterministic placement --------------------
__global__ void bucketize_det_kernel(const int* __restrict__ src,
                                     const int* __restrict__ dst,
                                     const int* __restrict__ chunkpre,
                                     const int* __restrict__ bptr,
                                     unsigned int* __restrict__ records,
                                     int nE, int NB) {
    __shared__ int lcur[NB_MAX];
    const int c  = blockIdx.x;
    const int e0 = c * CH, e1 = min(e0 + CH, nE);
    for (int b = threadIdx.x; b < NB; b += blockDim.x)
        lcur[b] = bptr[b] + chunkpre[(size_t)c * NB + b];
    __syncthreads();
    for (int e = e0 + threadIdx.x; e < e1; e += blockDim.x) {
        int d = dst[e];
        int b = d >> 7;
        int pos = atomicAdd(&lcur[b], 1);                  // LDS-only atomic
        records[pos] = (unsigned int)src[e] | ((unsigned int)(d & 127) << 17);
    }
}

// ---------------- build step 5: per-bucket hist+scan+rowptr+place ----------
__global__ void place_merge_kernel(const unsigned int* __restrict__ records,
                                   const int* __restrict__ bptr,
                                   int* __restrict__ rowptr,
                                   int* __restrict__ srcs_sorted,
                                   int N, int nE, int NB) {
    __shared__ int hist[RNODES];
    __shared__ int s[RNODES];
    __shared__ int lcur[RNODES];
    const int b    = blockIdx.x;
    const int base = b * RNODES;
    const int nn   = min(RNODES, N - base);
    const int beg  = bptr[b], end = bptr[b + 1];
    const int t    = threadIdx.x;

    if (t < RNODES) hist[t] = 0;
    __syncthreads();
    for (int i = beg + t; i < end; i += blockDim.x)
        atomicAdd(&hist[records[i] >> 17], 1);
    __syncthreads();

    if (t < RNODES) s[t] = hist[t];
    __syncthreads();
    for (int off = 1; off < RNODES; off <<= 1) {
        int v = (t < RNODES && t >= off) ? s[t - off] : 0;
        __syncthreads();
        if (t < RNODES && t >= off) s[t] += v;
        __syncthreads();
    }
    if (t < nn) {
        int ex = beg + s[t] - hist[t];
        rowptr[base + t] = ex;
        lcur[t] = ex;
    }
    if (b == NB - 1 && t == 0) rowptr[N] = nE;
    __syncthreads();

    for (int i = beg + t; i < end; i += blockDim.x) {
        unsigned int rec = records[i];
        int pos = atomicAdd(&lcur[rec >> 17], 1);
        srcs_sorted[pos] = (int)(rec & 0x1FFFFu);
    }
}

// ---------------- pull aggregation: staged unroll 16/4/1 -------------------
template <int F, bool SOFTMAX>
__global__ void gather_agg_kernel(const float* __restrict__ t,
                                  const int* __restrict__ rowptr,
                                  const int* __restrict__ srcs,
                                  const float* __restrict__ rootacc,
                                  float* __restrict__ out, int N) {
    int tid = blockIdx.x * blockDim.x + threadIdx.x;
    int n = tid / F;
    if (n >= N) return;
    int f = tid & (F - 1);
    const float* tf = t + f;
    int beg = rowptr[n], end = rowptr[n + 1];
    float sum = 0.0f;
    int e = beg;
    // stage 1: 16 concurrent gathers (mean degree ~16 -> usually one batch)
    for (; e + 16 <= end; e += 16) {
        int s[16];
        float v[16];
#pragma unroll
        for (int u = 0; u < 16; ++u) s[u] = srcs[e + u];
#pragma unroll
        for (int u = 0; u < 16; ++u) v[u] = tf[(long)s[u] * F];
#pragma unroll
        for (int u = 0; u < 16; ++u) sum += v[u];
    }
    // stage 2: 4-wide
    for (; e + 4 <= end; e += 4) {
        int s[4];
        float v[4];
#pragma unroll
        for (int u = 0; u < 4; ++u) s[u] = srcs[e + u];
#pragma unroll
        for (int u = 0; u < 4; ++u) v[u] = tf[(long)s[u] * F];
        sum += (v[0] + v[1]) + (v[2] + v[3]);
    }
    // tail (<=3)
    for (; e < end; ++e) sum += tf[(long)srcs[e] * F];

    float v = rootacc[(long)n * F + f] + sum;
    if (!SOFTMAX) {
        out[(long)n * F + f] = v;
    } else {
        float o = __shfl_xor(v, 1, 64);
        float m = fmaxf(v, o);
        float ev = __expf(v - m), eo = __expf(o - m);
        out[(long)n * F + f] = ev / (ev + eo);
    }
}

// ---------------- fallback (R2 atomic path) --------------------------------
template <int F>
__global__ void scatter_kernel(const float* __restrict__ t,
                               const int* __restrict__ src,
                               const int* __restrict__ dst,
                               float* __restrict__ acc, int nE) {
    int tid = blockIdx.x * blockDim.x + threadIdx.x;
    int e = tid / F;
    if (e >= nE) return;
    int f = tid & (F - 1);
    atomicAdd(acc + (long)dst[e] * F + f, t[(long)src[e] * F + f]);
}

__global__ void softmax2_kernel(const float* __restrict__ h, float* __restrict__ out, int N) {
    int n = blockIdx.x * blockDim.x + threadIdx.x;
    if (n >= N) return;
    float a = h[2 * n], b = h[2 * n + 1];
    float m = fmaxf(a, b);
    float ea = __expf(a - m), eb = __expf(b - m);
    float inv = 1.0f / (ea + eb);
    out[2 * n] = ea * inv;
    out[2 * n + 1] = eb * inv;
}

extern "C" void kernel_launch(void* const* d_in, const int* in_sizes, int n_in,
                              void* d_out, int out_size, void* d_ws, size_t ws_size,
                              hipStream_t stream) {
    const float* z      = (const float*)d_in[0];
    const int*   ei     = (const int*)d_in[1];
    const float* Wrel1  = (const float*)d_in[2];
    const float* Wroot1 = (const float*)d_in[3];
    const float* b1     = (const float*)d_in[4];
    const float* Wrel2  = (const float*)d_in[5];
    const float* Wroot2 = (const float*)d_in[6];
    const float* b2     = (const float*)d_in[7];
    const float* Wrel3  = (const float*)d_in[8];
    const float* Wroot3 = (const float*)d_in[9];
    const float* b3     = (const float*)d_in[10];

    const int N  = in_sizes[0] / 64;   // 100000
    const int nE = in_sizes[1] / 2;    // 1600000
    const int* src = ei;
    const int* dst = ei + nE;
    const int NB = (N + RNODES - 1) / RNODES;   // 782
    const int C  = (nE + CH - 1) / CH;          // 391 chunks

    // Float regions (ping-pong, 12.8 MB each):
    //   regionA: [records (build)] -> t1[N*32] -> { t2[N*16] | h2[N*16] }
    //   regionB: [chunkhist/gtotal/bptr (build)] -> h1[N*32] -> t3[N*2]
    float* regionA = (float*)d_ws;
    float* regionB = regionA + (size_t)N * 32;
    float* t1 = regionA;
    float* h1 = regionB;
    float* t2 = regionA;
    float* h2 = regionA + (size_t)N * 16;
    float* t3 = regionB;
    float* h3 = regionB + (size_t)N * 2;
    unsigned int* records = (unsigned int*)regionA;   // transient, pre-t1

    // Build tables in regionB (dead until h1 is written in layer 1):
    int* chunkhist = (int*)regionB;                   // [C][NB], C<=CMAX
    int* gtotal    = chunkhist + (size_t)CMAX * NB_MAX;
    int* bptr      = gtotal + NB_MAX;                 // [NB+1]
    // Persistent int region: rowptr[N+1], srcs_sorted[nE]
    int* ibase       = (int*)(regionB + (size_t)N * 32);
    int* rowptr      = ibase;
    int* srcs_sorted = rowptr + N + 1;

    size_t needed = (size_t)N * 64 * sizeof(float)
                  + ((size_t)N + 1 + (size_t)nE) * sizeof(int);
    size_t buildNeed = ((size_t)CMAX * NB_MAX + NB_MAX + NB_MAX + 1) * sizeof(int);

    const int B = 256;
    const int nodeBlocks = (N + B - 1) / B;
    const dim3 linGrid(nodeBlocks, 2);       // y=0: rel->t, y=1: root+b->acc
    const bool packOK = (N <= (1 << 17)) && (NB <= NB_MAX) && (C <= CMAX)
                      && ((size_t)nE * 4 <= (size_t)N * 32 * 4)
                      && (buildNeed <= (size_t)N * 32 * 4);

    if (ws_size >= needed && packOK) {
        // ---- build: zero-global-atomic deterministic CSR ----
        hist_chunked_kernel<<<C, 512, 0, stream>>>(dst, chunkhist, nE, NB);
        scan_chunkhist_kernel<<<NB, CMAX, 0, stream>>>(chunkhist, gtotal, C, NB);
        scan_buckets_kernel<<<1, NB_MAX, 0, stream>>>(gtotal, bptr, NB, nE);
        bucketize_det_kernel<<<C, 512, 0, stream>>>(src, dst, chunkhist, bptr, records, nE, NB);
        place_merge_kernel<<<NB, 512, 0, stream>>>(records, bptr, rowptr, srcs_sorted, N, nE, NB);

        // ---- Layer 1: 64 -> 32 ----
        linear2_kernel<64, 32, false><<<linGrid, B, 0, stream>>>(z, Wrel1, Wroot1, b1, t1, h1, N);
        gather_agg_kernel<32, false><<<((size_t)N * 32 + B - 1) / B, B, 0, stream>>>(
            t1, rowptr, srcs_sorted, h1, h1, N);

        // ---- Layer 2: 32 -> 16 ----
        linear2_kernel<32, 16, true><<<linGrid, B, 0, stream>>>(h1, Wrel2, Wroot2, b2, t2, h2, N);
        gather_agg_kernel<16, false><<<((size_t)N * 16 + B - 1) / B, B, 0, stream>>>(
            t2, rowptr, srcs_sorted, h2, h2, N);

        // ---- Layer 3: 16 -> 2, softmax fused ----
        linear2_kernel<16, 2, true><<<linGrid, B, 0, stream>>>(h2, Wrel3, Wroot3, b3, t3, h3, N);
        gather_agg_kernel<2, true><<<((size_t)N * 2 + B - 1) / B, B, 0, stream>>>(
            t3, rowptr, srcs_sorted, h3, (float*)d_out, N);
    } else {
        // ---- fallback: R2 atomic-scatter path ----
        linear2_kernel<64, 32, false><<<linGrid, B, 0, stream>>>(z, Wrel1, Wroot1, b1, t1, h1, N);
        scatter_kernel<32><<<((size_t)nE * 32 + B - 1) / B, B, 0, stream>>>(t1, src, dst, h1, nE);
        linear2_kernel<32, 16, true><<<linGrid, B, 0, stream>>>(h1, Wrel2, Wroot2, b2, t2, h2, N);
        scatter_kernel<16><<<((size_t)nE * 16 + B - 1) / B, B, 0, stream>>>(t2, src, dst, h2, nE);
        linear2_kernel<16, 2, true><<<linGrid, B, 0, stream>>>(h2, Wrel3, Wroot3, b3, t3, h3, N);
        scatter_kernel<2><<<((size_t)nE * 2 + B - 1) / B, B, 0, stream>>>(t3, src, dst, h3, nE);
        softmax2_kernel<<<nodeBlocks, B, 0, stream>>>(h3, (float*)d_out, N);
    }
}